// Round 6
// baseline (512.190 us; speedup 1.0000x reference)
//
#include <hip/hip_runtime.h>

#define NN 50000
#define NE 800000
#define F  64
#define FK 256
#define OUTF 256
#define CAP 48     // max in-degree bound: Binomial(800k,1/50k) mean 16; verified R1-R5
#define NT 3128    // row tiles: 391*8; 391*128 = 50048 padded rows
#define NB 391     // coarse buckets of 128 nodes (dst>>7)
#define BCAP 2560  // bucket capacity: mean 2048, sigma ~45 -> mean+11sigma

typedef __attribute__((ext_vector_type(8))) short s16x8;
typedef __attribute__((ext_vector_type(4))) float f32x4;

static __device__ __forceinline__ unsigned short f2bf(float f) {
    unsigned u = __float_as_uint(f);
    u += 0x7fffu + ((u >> 16) & 1u);
    return (unsigned short)(u >> 16);
}
static __device__ __forceinline__ float bf2f(int h) {
    return __uint_as_float(((unsigned)(h & 0xffff)) << 16);
}

// ---- pass A: bin edges into coarse dst-buckets (appends -> L2-mergeable) ----
__global__ void bin_kernel(const int* __restrict__ src, const int* __restrict__ dst,
                           int* __restrict__ bcnt, uint2* __restrict__ bbuf) {
    int e = blockIdx.x * blockDim.x + threadIdx.x;
    if (e < NE) {
        int d = dst[e], s = src[e];
        int bkt = d >> 7;
        int k = atomicAdd(&bcnt[bkt], 1);
        if (k < BCAP) bbuf[(size_t)bkt * BCAP + k] = make_uint2((unsigned)s, (unsigned)d);
    }
}

// ---- pass B: per-bucket CSR slice built in LDS, coalesced writeout ----------
__global__ __launch_bounds__(256) void build_kernel(const uint2* __restrict__ bbuf,
                                                    const int* __restrict__ bcnt,
                                                    int* __restrict__ cnt,
                                                    int* __restrict__ csr) {
    __shared__ int lcnt[128];
    __shared__ int lcsr[128 * CAP];
    int b = blockIdx.x;
    int t = threadIdx.x;
    if (t < 128) lcnt[t] = 0;
    __syncthreads();
    int m = min(bcnt[b], BCAP);
    for (int i = t; i < m; i += 256) {
        uint2 e = bbuf[(size_t)b * BCAP + i];
        int dl = (int)(e.y & 127u);
        int k = atomicAdd(&lcnt[dl], 1);
        if (k < CAP) lcsr[dl * CAP + k] = (int)e.x;
    }
    __syncthreads();
    int n0 = b * 128;
    if (t < 128 && n0 + t < NN) cnt[n0 + t] = lcnt[t];
    for (int i = t; i < 128 * CAP; i += 256) {
        int node = n0 + i / CAP;
        if (node < NN) csr[(size_t)n0 * CAP + i] = lcsr[i];
    }
}

__global__ void dsqrt_kernel(const int* __restrict__ cnt, float* __restrict__ dsq) {
    int n = blockIdx.x * blockDim.x + threadIdx.x;
    if (n < NN) dsq[n] = rsqrtf(fmaxf((float)cnt[n], 1.0f));
}

// Layouts:
//  XrowH: bf16 [node][col 0..2][f 0..63] (stride 192) -- gathered plane (hi)
//  XrowL: same shape -- lo residuals (combine only)
//  XfH:   frag-major A (hi): chunk (tile*8+k0)*64+lane, 16B = k-octet
//  WfH/WfL: frag-major B hi/lo

// ---- X0 ingest --------------------------------------------------------------
__global__ void copy0_kernel(const float* __restrict__ sig,
                             unsigned short* __restrict__ XrowH,
                             unsigned short* __restrict__ XrowL,
                             unsigned short* __restrict__ XfH) {
    int i = blockIdx.x * blockDim.x + threadIdx.x;   // NN*16
    if (i >= NN * 16) return;
    int n = i >> 4, fq = i & 15;
    float4 v = *(const float4*)&sig[n * F + fq * 4];
    unsigned short h0 = f2bf(v.x), h1 = f2bf(v.y), h2 = f2bf(v.z), h3 = f2bf(v.w);
    unsigned short l0 = f2bf(v.x - bf2f(h0)), l1 = f2bf(v.y - bf2f(h1));
    unsigned short l2 = f2bf(v.z - bf2f(h2)), l3 = f2bf(v.w - bf2f(h3));
    *(ushort4*)&XrowH[(size_t)n * 192 + fq * 4] = make_ushort4(h0, h1, h2, h3);
    *(ushort4*)&XrowL[(size_t)n * 192 + fq * 4] = make_ushort4(l0, l1, l2, l3);
    int t = n >> 4, m = n & 15;
    int k0 = fq >> 3, qq = (fq >> 1) & 3, half = fq & 1;
    size_t base = ((size_t)((t * 8 + k0) * 64 + qq * 16 + m)) * 8 + half * 4;
    *(ushort4*)&XfH[base] = make_ushort4(h0, h1, h2, h3);
}

// ---- W -> frag-major hi/lo --------------------------------------------------
__global__ void convw_kernel(const float* __restrict__ W,
                             unsigned short* __restrict__ WfH,
                             unsigned short* __restrict__ WfL) {
    int id = blockIdx.x * blockDim.x + threadIdx.x;  // 8192 chunks
    if (id >= 8192) return;
    int lane = id & 63, k0 = (id >> 6) & 7, ct = id >> 9;
    int n = lane & 15, q = lane >> 4;
    s16x8 h, l;
    #pragma unroll
    for (int j = 0; j < 8; ++j) {
        float x = W[(k0 * 32 + q * 8 + j) * OUTF + ct * 16 + n];
        unsigned short hh = f2bf(x);
        h[j] = (short)hh;
        l[j] = (short)f2bf(x - bf2f(hh));
    }
    ((s16x8*)WfH)[id] = h;
    ((s16x8*)WfL)[id] = l;
}

// ---- fused Laplacian gather (8 slots x 16B loads) + Chebyshev combine -------
__global__ __launch_bounds__(256) void lap_kernel(const int* __restrict__ cnt,
                                                  const int* __restrict__ csr,
                                                  const float* __restrict__ dsq,
                                                  const float* __restrict__ lm,
                                                  unsigned short* __restrict__ XrowH,
                                                  unsigned short* __restrict__ XrowL,
                                                  unsigned short* __restrict__ XfH, int p) {
    int wid  = (blockIdx.x * blockDim.x + threadIdx.x) >> 6;   // node
    int lane = threadIdx.x & 63;
    int s = lane >> 3;      // edge slot 0..7
    int o = lane & 7;       // feature octet (8 feats, 16B)
    if (wid >= NN) return;
    int n  = wid;
    int dg = min(cnt[n], CAP);
    int cin = p - 1;

    float acc[8];
    #pragma unroll
    for (int j = 0; j < 8; ++j) acc[j] = 0.f;

    for (int k = s; k < dg; k += 16) {
        int e0 = csr[n * CAP + k];
        bool pr = (k + 8) < dg;
        int e1 = pr ? csr[n * CAP + k + 8] : e0;
        float d0 = dsq[e0];
        float d1 = pr ? dsq[e1] : 0.f;
        s16x8 x0 = *(const s16x8*)&XrowH[((size_t)e0 * 3 + cin) * 64 + o * 8];
        s16x8 x1 = *(const s16x8*)&XrowH[((size_t)e1 * 3 + cin) * 64 + o * 8];
        #pragma unroll
        for (int j = 0; j < 8; ++j)
            acc[j] += bf2f(x0[j]) * d0 + bf2f(x1[j]) * d1;
    }
    #pragma unroll
    for (int j = 0; j < 8; ++j) {
        acc[j] += __shfl_xor(acc[j], 8);
        acc[j] += __shfl_xor(acc[j], 16);
        acc[j] += __shfl_xor(acc[j], 32);
    }

    float rn = 2.0f / lm[0];
    float dn = dsq[n];
    s16x8 xh = *(const s16x8*)&XrowH[((size_t)n * 3 + cin) * 64 + o * 8];
    s16x8 xl = *(const s16x8*)&XrowL[((size_t)n * 3 + cin) * 64 + o * 8];
    float r[8];
    if (p == 1) {
        float c1 = rn - 1.0f;
        #pragma unroll
        for (int j = 0; j < 8; ++j)
            r[j] = -rn * dn * acc[j] + (bf2f(xh[j]) + bf2f(xl[j])) * c1;
    } else {
        s16x8 zh = *(const s16x8*)&XrowH[((size_t)n * 3 + (p - 2)) * 64 + o * 8];
        s16x8 zl = *(const s16x8*)&XrowL[((size_t)n * 3 + (p - 2)) * 64 + o * 8];
        float c1 = 2.0f * (rn - 1.0f);
        #pragma unroll
        for (int j = 0; j < 8; ++j)
            r[j] = -2.0f * rn * dn * acc[j] + (bf2f(xh[j]) + bf2f(xl[j])) * c1
                 - (bf2f(zh[j]) + bf2f(zl[j]));
    }
    s16x8 h;
    #pragma unroll
    for (int j = 0; j < 8; ++j) h[j] = (short)f2bf(r[j]);

    if (s == 0 && p < 3) {
        *(s16x8*)&XrowH[((size_t)n * 3 + p) * 64 + o * 8] = h;
    } else if (s == 1 && p < 3) {
        s16x8 l;
        #pragma unroll
        for (int j = 0; j < 8; ++j) l[j] = (short)f2bf(r[j] - bf2f(h[j]));
        *(s16x8*)&XrowL[((size_t)n * 3 + p) * 64 + o * 8] = l;
    } else if (s == 2) {
        int t = n >> 4, m = n & 15;
        int k0 = p * 2 + (o >> 2), qq = o & 3;
        size_t chunk = (size_t)((t * 8 + k0) * 64 + qq * 16 + m);
        *(s16x8*)&XfH[chunk * 8] = h;
    }
}

// ---- GEMM: A hi-only, wave 64x64, block 128x128, k0 double-buffered ---------
__global__ __launch_bounds__(256, 2) void gemm_kernel(const unsigned short* __restrict__ XfH,
                                                      const unsigned short* __restrict__ WfH,
                                                      const unsigned short* __restrict__ WfL,
                                                      const float* __restrict__ b,
                                                      float* __restrict__ out) {
    int lane = threadIdx.x & 63;
    int w    = threadIdx.x >> 6;     // 0..3
    int rh = w & 1, cg = w >> 1;     // row half, col group (0..1 each)
    int m = lane & 15, q = lane >> 4;
    int rowblk = blockIdx.x >> 1;
    int ch = blockIdx.x & 1;         // col half (128 cols)
    int bt0 = rowblk * 8 + rh * 4;
    const s16x8* AH = (const s16x8*)XfH;
    const s16x8* BH = (const s16x8*)WfH;
    const s16x8* BL = (const s16x8*)WfL;

    f32x4 acc[4][4];
    #pragma unroll
    for (int rt = 0; rt < 4; ++rt)
        #pragma unroll
        for (int c = 0; c < 4; ++c) acc[rt][c] = (f32x4){0.f, 0.f, 0.f, 0.f};

    s16x8 a[2][4], bh[2][4], bl[2][4];
    #pragma unroll
    for (int rt = 0; rt < 4; ++rt) a[0][rt] = AH[((bt0 + rt) * 8 + 0) * 64 + lane];
    #pragma unroll
    for (int c = 0; c < 4; ++c) {
        int ct = ch * 8 + cg * 4 + c;
        bh[0][c] = BH[(ct * 8 + 0) * 64 + lane];
        bl[0][c] = BL[(ct * 8 + 0) * 64 + lane];
    }

    #pragma unroll
    for (int k0 = 0; k0 < 8; ++k0) {
        int cur = k0 & 1, nxt = cur ^ 1;
        if (k0 < 7) {
            #pragma unroll
            for (int rt = 0; rt < 4; ++rt)
                a[nxt][rt] = AH[((bt0 + rt) * 8 + k0 + 1) * 64 + lane];
            #pragma unroll
            for (int c = 0; c < 4; ++c) {
                int ct = ch * 8 + cg * 4 + c;
                bh[nxt][c] = BH[(ct * 8 + k0 + 1) * 64 + lane];
                bl[nxt][c] = BL[(ct * 8 + k0 + 1) * 64 + lane];
            }
        }
        #pragma unroll
        for (int c = 0; c < 4; ++c)
            #pragma unroll
            for (int rt = 0; rt < 4; ++rt) {
                acc[rt][c] = __builtin_amdgcn_mfma_f32_16x16x32_bf16(a[cur][rt], bh[cur][c], acc[rt][c], 0, 0, 0);
                acc[rt][c] = __builtin_amdgcn_mfma_f32_16x16x32_bf16(a[cur][rt], bl[cur][c], acc[rt][c], 0, 0, 0);
            }
    }

    #pragma unroll
    for (int rt = 0; rt < 4; ++rt) {
        int rbase = (bt0 + rt) * 16 + q * 4;
        #pragma unroll
        for (int c = 0; c < 4; ++c) {
            int col = (ch * 8 + cg * 4 + c) * 16 + m;
            float bv = b[col];
            #pragma unroll
            for (int i = 0; i < 4; ++i) {
                int r = rbase + i;
                if (r < NN) out[r * OUTF + col] = fmaxf(acc[rt][c][i] + bv, 0.0f);
            }
        }
    }
}

// ---- host -------------------------------------------------------------------
extern "C" void kernel_launch(void* const* d_in, const int* in_sizes, int n_in,
                              void* d_out, int out_size, void* d_ws, size_t ws_size,
                              hipStream_t stream) {
    const float* signal     = (const float*)d_in[0];
    const int*   src        = (const int*)  d_in[1];
    const int*   dst        = (const int*)  d_in[2];
    const float* lambda_max = (const float*)d_in[3];
    const float* W          = (const float*)d_in[4];
    const float* b          = (const float*)d_in[5];
    float* out = (float*)d_out;

    // ws: bcnt[512]i | cnt[NN]i | dsq[NN]f | csr[NN*CAP]i | bbuf[NB*BCAP]u2
    //     | XrowH[NN*192]u16 | XrowL[NN*192]u16 | XfH[NT*4096]u16 | WfH/WfL[64K]u16
    // ~= 82.3 MB (< 99.9 MB proven present in R4)
    int*   bcnt = (int*)d_ws;
    int*   cnt  = bcnt + 512;
    float* dsq  = (float*)(cnt + NN);
    int*   csr  = (int*)(dsq + NN);
    uint2* bbuf = (uint2*)(csr + (size_t)NN * CAP);
    unsigned short* XrowH = (unsigned short*)(bbuf + (size_t)NB * BCAP);
    unsigned short* XrowL = XrowH + (size_t)NN * 192;
    unsigned short* XfH   = XrowL + (size_t)NN * 192;
    unsigned short* WfH   = XfH + (size_t)NT * 4096;
    unsigned short* WfL   = WfH + 65536;

    hipMemsetAsync(bcnt, 0, 512 * sizeof(int), stream);
    bin_kernel<<<(NE + 255) / 256, 256, 0, stream>>>(src, dst, bcnt, bbuf);
    build_kernel<<<NB, 256, 0, stream>>>(bbuf, bcnt, cnt, csr);
    dsqrt_kernel<<<(NN + 255) / 256, 256, 0, stream>>>(cnt, dsq);
    copy0_kernel<<<(NN * 16 + 255) / 256, 256, 0, stream>>>(signal, XrowH, XrowL, XfH);
    convw_kernel<<<32, 256, 0, stream>>>(W, WfH, WfL);

    for (int p = 1; p <= 3; ++p)
        lap_kernel<<<NN / 4, 256, 0, stream>>>(cnt, csr, dsq, lambda_max, XrowH, XrowL, XfH, p);

    gemm_kernel<<<NB * 2, 256, 0, stream>>>(XfH, WfH, WfL, b, out);
}

// Round 7
// 277.217 us; speedup vs baseline: 1.8476x; 1.8476x over previous
//
#include <hip/hip_runtime.h>

#define NN 50000
#define NE 800000
#define F  64
#define FK 256
#define OUTF 256
#define CAP 48      // max in-degree bound: Binomial(800k,1/50k) mean 16; verified R1-R6
#define NT 3128     // row tiles: 391*8; 391*128 = 50048 padded rows
#define NBF 12500   // fine buckets of 4 nodes (dst>>2)
#define BCAPF 128   // bucket cap: mean 64, sigma 8 -> 8 sigma headroom

typedef __attribute__((ext_vector_type(8))) short s16x8;
typedef __attribute__((ext_vector_type(4))) float f32x4;

static __device__ __forceinline__ unsigned short f2bf(float f) {
    unsigned u = __float_as_uint(f);
    u += 0x7fffu + ((u >> 16) & 1u);
    return (unsigned short)(u >> 16);
}
static __device__ __forceinline__ float bf2f(int h) {
    return __uint_as_float(((unsigned)(h & 0xffff)) << 16);
}

// ---- pass A: bin edges into fine dst-buckets (4 nodes/bucket) ---------------
// 64 atomics/counter (~9us serial floor at 137ns/same-addr atomic, measured R6);
// packed 4B payload appends are L2-mergeable (active lines = 12.5k = 800KB).
__global__ void bin_kernel(const int* __restrict__ src, const int* __restrict__ dst,
                           int* __restrict__ bcnt, unsigned* __restrict__ bbuf) {
    int e = blockIdx.x * blockDim.x + threadIdx.x;
    if (e < NE) {
        int d = dst[e], s = src[e];
        int bkt = d >> 2;
        int k = atomicAdd(&bcnt[bkt], 1);
        if (k < BCAPF) bbuf[bkt * BCAPF + k] = (unsigned)s | ((unsigned)(d & 3) << 17);
    }
}

// ---- pass B: block per 128 nodes = 32 buckets; LDS CSR; coalesced writeout --
__global__ __launch_bounds__(256) void build_kernel(const unsigned* __restrict__ bbuf,
                                                    const int* __restrict__ bcnt,
                                                    int* __restrict__ cnt,
                                                    int* __restrict__ csr) {
    __shared__ int lcnt[128];
    __shared__ int lcsr[128 * CAP];
    int b = blockIdx.x;
    int t = threadIdx.x;
    if (t < 128) lcnt[t] = 0;
    __syncthreads();
    int bi  = t >> 3;              // bucket 0..31 within block (8 threads each)
    int bkt = b * 32 + bi;
    int m   = (bkt < NBF) ? min(bcnt[bkt], BCAPF) : 0;
    for (int i = t & 7; i < m; i += 8) {
        unsigned v = bbuf[bkt * BCAPF + i];
        int dl = bi * 4 + (int)(v >> 17);
        int k = atomicAdd(&lcnt[dl], 1);
        if (k < CAP) lcsr[dl * CAP + k] = (int)(v & 0x1FFFFu);
    }
    __syncthreads();
    int n0 = b * 128;
    if (t < 128 && n0 + t < NN) cnt[n0 + t] = lcnt[t];
    for (int i = t; i < 128 * CAP; i += 256) {
        int node = n0 + i / CAP;
        if (node < NN) csr[(size_t)n0 * CAP + i] = lcsr[i];
    }
}

__global__ void dsqrt_kernel(const int* __restrict__ cnt, float* __restrict__ dsq) {
    int n = blockIdx.x * blockDim.x + threadIdx.x;
    if (n < NN) dsq[n] = rsqrtf(fmaxf((float)cnt[n], 1.0f));
}

// Layouts:
//  XrowH: bf16 [node][col 0..2][f 0..63] (stride 192) -- gathered plane (hi)
//  XrowL: same shape -- lo residuals (combine only)
//  XfH:   frag-major A (hi): chunk (tile*8+k0)*64+lane, 16B = k-octet
//  WfH/WfL: frag-major B hi/lo

// ---- X0 ingest --------------------------------------------------------------
__global__ void copy0_kernel(const float* __restrict__ sig,
                             unsigned short* __restrict__ XrowH,
                             unsigned short* __restrict__ XrowL,
                             unsigned short* __restrict__ XfH) {
    int i = blockIdx.x * blockDim.x + threadIdx.x;   // NN*16
    if (i >= NN * 16) return;
    int n = i >> 4, fq = i & 15;
    float4 v = *(const float4*)&sig[n * F + fq * 4];
    unsigned short h0 = f2bf(v.x), h1 = f2bf(v.y), h2 = f2bf(v.z), h3 = f2bf(v.w);
    unsigned short l0 = f2bf(v.x - bf2f(h0)), l1 = f2bf(v.y - bf2f(h1));
    unsigned short l2 = f2bf(v.z - bf2f(h2)), l3 = f2bf(v.w - bf2f(h3));
    *(ushort4*)&XrowH[(size_t)n * 192 + fq * 4] = make_ushort4(h0, h1, h2, h3);
    *(ushort4*)&XrowL[(size_t)n * 192 + fq * 4] = make_ushort4(l0, l1, l2, l3);
    int t = n >> 4, m = n & 15;
    int k0 = fq >> 3, qq = (fq >> 1) & 3, half = fq & 1;
    size_t base = ((size_t)((t * 8 + k0) * 64 + qq * 16 + m)) * 8 + half * 4;
    *(ushort4*)&XfH[base] = make_ushort4(h0, h1, h2, h3);
}

// ---- W -> frag-major hi/lo --------------------------------------------------
__global__ void convw_kernel(const float* __restrict__ W,
                             unsigned short* __restrict__ WfH,
                             unsigned short* __restrict__ WfL) {
    int id = blockIdx.x * blockDim.x + threadIdx.x;  // 8192 chunks
    if (id >= 8192) return;
    int lane = id & 63, k0 = (id >> 6) & 7, ct = id >> 9;
    int n = lane & 15, q = lane >> 4;
    s16x8 h, l;
    #pragma unroll
    for (int j = 0; j < 8; ++j) {
        float x = W[(k0 * 32 + q * 8 + j) * OUTF + ct * 16 + n];
        unsigned short hh = f2bf(x);
        h[j] = (short)hh;
        l[j] = (short)f2bf(x - bf2f(hh));
    }
    ((s16x8*)WfH)[id] = h;
    ((s16x8*)WfL)[id] = l;
}

// ---- fused Laplacian gather (8 slots x 16B loads) + Chebyshev combine -------
__global__ __launch_bounds__(256) void lap_kernel(const int* __restrict__ cnt,
                                                  const int* __restrict__ csr,
                                                  const float* __restrict__ dsq,
                                                  const float* __restrict__ lm,
                                                  unsigned short* __restrict__ XrowH,
                                                  unsigned short* __restrict__ XrowL,
                                                  unsigned short* __restrict__ XfH, int p) {
    int wid  = (blockIdx.x * blockDim.x + threadIdx.x) >> 6;   // node
    int lane = threadIdx.x & 63;
    int s = lane >> 3;      // edge slot 0..7
    int o = lane & 7;       // feature octet (8 feats, 16B)
    if (wid >= NN) return;
    int n  = wid;
    int dg = min(cnt[n], CAP);
    int cin = p - 1;

    float acc[8];
    #pragma unroll
    for (int j = 0; j < 8; ++j) acc[j] = 0.f;

    for (int k = s; k < dg; k += 16) {
        int e0 = csr[n * CAP + k];
        bool pr = (k + 8) < dg;
        int e1 = pr ? csr[n * CAP + k + 8] : e0;
        float d0 = dsq[e0];
        float d1 = pr ? dsq[e1] : 0.f;
        s16x8 x0 = *(const s16x8*)&XrowH[((size_t)e0 * 3 + cin) * 64 + o * 8];
        s16x8 x1 = *(const s16x8*)&XrowH[((size_t)e1 * 3 + cin) * 64 + o * 8];
        #pragma unroll
        for (int j = 0; j < 8; ++j)
            acc[j] += bf2f(x0[j]) * d0 + bf2f(x1[j]) * d1;
    }
    #pragma unroll
    for (int j = 0; j < 8; ++j) {
        acc[j] += __shfl_xor(acc[j], 8);
        acc[j] += __shfl_xor(acc[j], 16);
        acc[j] += __shfl_xor(acc[j], 32);
    }

    float rn = 2.0f / lm[0];
    float dn = dsq[n];
    s16x8 xh = *(const s16x8*)&XrowH[((size_t)n * 3 + cin) * 64 + o * 8];
    s16x8 xl = *(const s16x8*)&XrowL[((size_t)n * 3 + cin) * 64 + o * 8];
    float r[8];
    if (p == 1) {
        float c1 = rn - 1.0f;
        #pragma unroll
        for (int j = 0; j < 8; ++j)
            r[j] = -rn * dn * acc[j] + (bf2f(xh[j]) + bf2f(xl[j])) * c1;
    } else {
        s16x8 zh = *(const s16x8*)&XrowH[((size_t)n * 3 + (p - 2)) * 64 + o * 8];
        s16x8 zl = *(const s16x8*)&XrowL[((size_t)n * 3 + (p - 2)) * 64 + o * 8];
        float c1 = 2.0f * (rn - 1.0f);
        #pragma unroll
        for (int j = 0; j < 8; ++j)
            r[j] = -2.0f * rn * dn * acc[j] + (bf2f(xh[j]) + bf2f(xl[j])) * c1
                 - (bf2f(zh[j]) + bf2f(zl[j]));
    }
    s16x8 h;
    #pragma unroll
    for (int j = 0; j < 8; ++j) h[j] = (short)f2bf(r[j]);

    if (s == 0 && p < 3) {
        *(s16x8*)&XrowH[((size_t)n * 3 + p) * 64 + o * 8] = h;
    } else if (s == 1 && p < 3) {
        s16x8 l;
        #pragma unroll
        for (int j = 0; j < 8; ++j) l[j] = (short)f2bf(r[j] - bf2f(h[j]));
        *(s16x8*)&XrowL[((size_t)n * 3 + p) * 64 + o * 8] = l;
    } else if (s == 2) {
        int t = n >> 4, m = n & 15;
        int k0 = p * 2 + (o >> 2), qq = o & 3;
        size_t chunk = (size_t)((t * 8 + k0) * 64 + qq * 16 + m);
        *(s16x8*)&XfH[chunk * 8] = h;
    }
}

// ---- GEMM: A hi-only, wave 64x64, block 128x128, k0 double-buffered ---------
__global__ __launch_bounds__(256, 2) void gemm_kernel(const unsigned short* __restrict__ XfH,
                                                      const unsigned short* __restrict__ WfH,
                                                      const unsigned short* __restrict__ WfL,
                                                      const float* __restrict__ b,
                                                      float* __restrict__ out) {
    int lane = threadIdx.x & 63;
    int w    = threadIdx.x >> 6;     // 0..3
    int rh = w & 1, cg = w >> 1;     // row half, col group (0..1 each)
    int m = lane & 15, q = lane >> 4;
    int rowblk = blockIdx.x >> 1;
    int ch = blockIdx.x & 1;         // col half (128 cols)
    int bt0 = rowblk * 8 + rh * 4;
    const s16x8* AH = (const s16x8*)XfH;
    const s16x8* BH = (const s16x8*)WfH;
    const s16x8* BL = (const s16x8*)WfL;

    f32x4 acc[4][4];
    #pragma unroll
    for (int rt = 0; rt < 4; ++rt)
        #pragma unroll
        for (int c = 0; c < 4; ++c) acc[rt][c] = (f32x4){0.f, 0.f, 0.f, 0.f};

    s16x8 a[2][4], bh[2][4], bl[2][4];
    #pragma unroll
    for (int rt = 0; rt < 4; ++rt) a[0][rt] = AH[((bt0 + rt) * 8 + 0) * 64 + lane];
    #pragma unroll
    for (int c = 0; c < 4; ++c) {
        int ct = ch * 8 + cg * 4 + c;
        bh[0][c] = BH[(ct * 8 + 0) * 64 + lane];
        bl[0][c] = BL[(ct * 8 + 0) * 64 + lane];
    }

    #pragma unroll
    for (int k0 = 0; k0 < 8; ++k0) {
        int cur = k0 & 1, nxt = cur ^ 1;
        if (k0 < 7) {
            #pragma unroll
            for (int rt = 0; rt < 4; ++rt)
                a[nxt][rt] = AH[((bt0 + rt) * 8 + k0 + 1) * 64 + lane];
            #pragma unroll
            for (int c = 0; c < 4; ++c) {
                int ct = ch * 8 + cg * 4 + c;
                bh[nxt][c] = BH[(ct * 8 + k0 + 1) * 64 + lane];
                bl[nxt][c] = BL[(ct * 8 + k0 + 1) * 64 + lane];
            }
        }
        #pragma unroll
        for (int c = 0; c < 4; ++c)
            #pragma unroll
            for (int rt = 0; rt < 4; ++rt) {
                acc[rt][c] = __builtin_amdgcn_mfma_f32_16x16x32_bf16(a[cur][rt], bh[cur][c], acc[rt][c], 0, 0, 0);
                acc[rt][c] = __builtin_amdgcn_mfma_f32_16x16x32_bf16(a[cur][rt], bl[cur][c], acc[rt][c], 0, 0, 0);
            }
    }

    #pragma unroll
    for (int rt = 0; rt < 4; ++rt) {
        int rbase = (bt0 + rt) * 16 + q * 4;
        #pragma unroll
        for (int c = 0; c < 4; ++c) {
            int col = (ch * 8 + cg * 4 + c) * 16 + m;
            float bv = b[col];
            #pragma unroll
            for (int i = 0; i < 4; ++i) {
                int r = rbase + i;
                if (r < NN) out[r * OUTF + col] = fmaxf(acc[rt][c][i] + bv, 0.0f);
            }
        }
    }
}

// ---- host -------------------------------------------------------------------
extern "C" void kernel_launch(void* const* d_in, const int* in_sizes, int n_in,
                              void* d_out, int out_size, void* d_ws, size_t ws_size,
                              hipStream_t stream) {
    const float* signal     = (const float*)d_in[0];
    const int*   src        = (const int*)  d_in[1];
    const int*   dst        = (const int*)  d_in[2];
    const float* lambda_max = (const float*)d_in[3];
    const float* W          = (const float*)d_in[4];
    const float* b          = (const float*)d_in[5];
    float* out = (float*)d_out;

    // ws: bcnt[12544]i | cnt[NN]i | dsq[NN]f | csr[NN*CAP]i | bbuf[NBF*BCAPF]u32
    //     | XrowH[NN*192]u16 | XrowL[NN*192]u16 | XfH[NT*4096]u16 | WfH/WfL[64K]u16
    // ~= 80.8 MB (< 99.9 MB proven present in R4)
    int*      bcnt = (int*)d_ws;
    int*      cnt  = bcnt + 12544;
    float*    dsq  = (float*)(cnt + NN);
    int*      csr  = (int*)(dsq + NN);
    unsigned* bbuf = (unsigned*)(csr + (size_t)NN * CAP);
    unsigned short* XrowH = (unsigned short*)(bbuf + (size_t)NBF * BCAPF);
    unsigned short* XrowL = XrowH + (size_t)NN * 192;
    unsigned short* XfH   = XrowL + (size_t)NN * 192;
    unsigned short* WfH   = XfH + (size_t)NT * 4096;
    unsigned short* WfL   = WfH + 65536;

    hipMemsetAsync(bcnt, 0, 12544 * sizeof(int), stream);
    bin_kernel<<<(NE + 255) / 256, 256, 0, stream>>>(src, dst, bcnt, bbuf);
    build_kernel<<<391, 256, 0, stream>>>(bbuf, bcnt, cnt, csr);
    dsqrt_kernel<<<(NN + 255) / 256, 256, 0, stream>>>(cnt, dsq);
    copy0_kernel<<<(NN * 16 + 255) / 256, 256, 0, stream>>>(signal, XrowH, XrowL, XfH);
    convw_kernel<<<32, 256, 0, stream>>>(W, WfH, WfL);

    for (int p = 1; p <= 3; ++p)
        lap_kernel<<<NN / 4, 256, 0, stream>>>(cnt, csr, dsq, lambda_max, XrowH, XrowL, XfH, p);

    gemm_kernel<<<391 * 2, 256, 0, stream>>>(XfH, WfH, WfL, b, out);
}

// Round 8
// 262.989 us; speedup vs baseline: 1.9476x; 1.0541x over previous
//
#include <hip/hip_runtime.h>

#define NN 50000
#define NE 800000
#define F  64
#define FK 256
#define OUTF 256
#define CAP 48      // max in-degree bound: Binomial(800k,1/50k) mean 16; verified R1-R7
#define NT 3128     // row tiles: 391*8; 391*128 = 50048 padded rows
#define NBKT 196    // counting-sort buckets: 256 nodes each (dst>>8)
#define NBLK 196    // edge blocks: 4096 edges each (196*4096 >= 800000)
#define EB 4096

typedef __attribute__((ext_vector_type(8))) short s16x8;
typedef __attribute__((ext_vector_type(4))) float f32x4;

static __device__ __forceinline__ unsigned short f2bf(float f) {
    unsigned u = __float_as_uint(f);
    u += 0x7fffu + ((u >> 16) & 1u);
    return (unsigned short)(u >> 16);
}
static __device__ __forceinline__ float bf2f(int h) {
    return __uint_as_float(((unsigned)(h & 0xffff)) << 16);
}

// ==== counting-sort CSR build (no global atomics, deterministic) ============

// hist: per-block LDS histogram over 196 coarse buckets
__global__ __launch_bounds__(1024) void histk(const int* __restrict__ dst,
                                              int* __restrict__ blockhist) {
    __shared__ int h[NBKT];
    int t = threadIdx.x, blk = blockIdx.x;
    if (t < NBKT) h[t] = 0;
    __syncthreads();
    int e0 = blk * EB;
    for (int i = t; i < EB; i += 1024) {
        int e = e0 + i;
        if (e < NE) atomicAdd(&h[dst[e] >> 8], 1);
    }
    __syncthreads();
    if (t < NBKT) blockhist[t * NBLK + blk] = h[t];   // bucket-major
}

// scank: per bucket, exclusive scan over 196 block counts
__global__ __launch_bounds__(256) void scank(const int* __restrict__ blockhist,
                                             int* __restrict__ blockpre,
                                             int* __restrict__ colsum) {
    __shared__ int v[256];
    int t = threadIdx.x, b = blockIdx.x;
    int x = (t < NBLK) ? blockhist[b * NBLK + t] : 0;
    v[t] = x;
    __syncthreads();
    for (int off = 1; off < 256; off <<= 1) {
        int y = (t >= off) ? v[t - off] : 0;
        __syncthreads();
        v[t] += y;
        __syncthreads();
    }
    if (t < NBLK) blockpre[b * NBLK + t] = v[t] - x;  // exclusive
    if (t == 255) colsum[b] = v[255];
}

// bbasek: exclusive scan of 196 bucket totals
__global__ __launch_bounds__(256) void bbasek(const int* __restrict__ colsum,
                                              int* __restrict__ bucketbase) {
    __shared__ int v[256];
    int t = threadIdx.x;
    int x = (t < NBKT) ? colsum[t] : 0;
    v[t] = x;
    __syncthreads();
    for (int off = 1; off < 256; off <<= 1) {
        int y = (t >= off) ? v[t - off] : 0;
        __syncthreads();
        v[t] += y;
        __syncthreads();
    }
    if (t < NBKT) bucketbase[t] = v[t] - x;
}

// scatk: LDS-sort block's edges by bucket, write to exact global positions
__global__ __launch_bounds__(1024) void scatk(const int* __restrict__ src,
                                              const int* __restrict__ dst,
                                              const int* __restrict__ blockpre,
                                              const int* __restrict__ bucketbase,
                                              unsigned* __restrict__ ebuf) {
    __shared__ int h[NBKT];        // local counts -> preserved
    __shared__ int rk[NBKT];       // running position
    __shared__ int gb[NBKT];       // gpos = gb[bkt] + pos
    __shared__ int s[256];
    __shared__ unsigned sv[EB];
    __shared__ int sg[EB];
    int t = threadIdx.x, blk = blockIdx.x;
    int e0 = blk * EB;
    if (t < NBKT) h[t] = 0;
    __syncthreads();
    for (int i = t; i < EB; i += 1024) {
        int e = e0 + i;
        if (e < NE) atomicAdd(&h[dst[e] >> 8], 1);
    }
    __syncthreads();
    // exclusive scan of h (196) using first 256 threads
    if (t < 256) s[t] = (t < NBKT) ? h[t] : 0;
    __syncthreads();
    for (int off = 1; off < 256; off <<= 1) {
        int y = (t < 256 && t >= off) ? s[t - off] : 0;
        __syncthreads();
        if (t < 256) s[t] += y;
        __syncthreads();
    }
    if (t < NBKT) {
        int ex = s[t] - h[t];                       // local base
        rk[t] = ex;
        gb[t] = bucketbase[t] + blockpre[t * NBLK + blk] - ex;
    }
    __syncthreads();
    for (int i = t; i < EB; i += 1024) {
        int e = e0 + i;
        if (e < NE) {
            int d = dst[e];
            int bkt = d >> 8;
            int pos = atomicAdd(&rk[bkt], 1);
            sv[pos] = (unsigned)src[e] | ((unsigned)(d & 255) << 16);
            sg[pos] = gb[bkt] + pos;
        }
    }
    __syncthreads();
    int nloc = min(EB, NE - e0);
    for (int i = t; i < nloc; i += 1024)
        ebuf[sg[i]] = sv[i];                        // long dense runs per bucket
}

// buildk: per-bucket CSR slice in LDS; fused dsq; coalesced writeout
__global__ __launch_bounds__(256) void buildk(const unsigned* __restrict__ ebuf,
                                              const int* __restrict__ bucketbase,
                                              const int* __restrict__ colsum,
                                              int* __restrict__ cnt,
                                              float* __restrict__ dsq,
                                              int* __restrict__ csr) {
    __shared__ int lcnt[256];
    __shared__ int lcsr[256 * CAP];                 // 49 KB
    int b = blockIdx.x, t = threadIdx.x;
    lcnt[t] = 0;
    __syncthreads();
    int base = bucketbase[b];
    int m = colsum[b];
    for (int i = t; i < m; i += 256) {
        unsigned v = ebuf[base + i];                // contiguous, coalesced
        int dl = (int)((v >> 16) & 255u);
        int k = atomicAdd(&lcnt[dl], 1);
        if (k < CAP) lcsr[dl * CAP + k] = (int)(v & 0xFFFFu);
    }
    __syncthreads();
    int n0 = b * 256;
    if (n0 + t < NN) {
        int c = lcnt[t];
        cnt[n0 + t] = c;
        dsq[n0 + t] = rsqrtf(fmaxf((float)c, 1.0f));
    }
    for (int i = t; i < 256 * CAP; i += 256) {
        int node = n0 + i / CAP;
        if (node < NN) csr[(size_t)n0 * CAP + i] = lcsr[i];
    }
}

// ==== feature pipeline (unchanged from R7) ==================================
// Layouts:
//  XrowH: bf16 [node][col 0..2][f 0..63] (stride 192) -- gathered plane (hi)
//  XrowL: same shape -- lo residuals (combine only)
//  XfH:   frag-major A (hi): chunk (tile*8+k0)*64+lane, 16B = k-octet
//  WfH/WfL: frag-major B hi/lo

__global__ void copy0_kernel(const float* __restrict__ sig,
                             unsigned short* __restrict__ XrowH,
                             unsigned short* __restrict__ XrowL,
                             unsigned short* __restrict__ XfH) {
    int i = blockIdx.x * blockDim.x + threadIdx.x;   // NN*16
    if (i >= NN * 16) return;
    int n = i >> 4, fq = i & 15;
    float4 v = *(const float4*)&sig[n * F + fq * 4];
    unsigned short h0 = f2bf(v.x), h1 = f2bf(v.y), h2 = f2bf(v.z), h3 = f2bf(v.w);
    unsigned short l0 = f2bf(v.x - bf2f(h0)), l1 = f2bf(v.y - bf2f(h1));
    unsigned short l2 = f2bf(v.z - bf2f(h2)), l3 = f2bf(v.w - bf2f(h3));
    *(ushort4*)&XrowH[(size_t)n * 192 + fq * 4] = make_ushort4(h0, h1, h2, h3);
    *(ushort4*)&XrowL[(size_t)n * 192 + fq * 4] = make_ushort4(l0, l1, l2, l3);
    int t = n >> 4, m = n & 15;
    int k0 = fq >> 3, qq = (fq >> 1) & 3, half = fq & 1;
    size_t base = ((size_t)((t * 8 + k0) * 64 + qq * 16 + m)) * 8 + half * 4;
    *(ushort4*)&XfH[base] = make_ushort4(h0, h1, h2, h3);
}

__global__ void convw_kernel(const float* __restrict__ W,
                             unsigned short* __restrict__ WfH,
                             unsigned short* __restrict__ WfL) {
    int id = blockIdx.x * blockDim.x + threadIdx.x;  // 8192 chunks
    if (id >= 8192) return;
    int lane = id & 63, k0 = (id >> 6) & 7, ct = id >> 9;
    int n = lane & 15, q = lane >> 4;
    s16x8 h, l;
    #pragma unroll
    for (int j = 0; j < 8; ++j) {
        float x = W[(k0 * 32 + q * 8 + j) * OUTF + ct * 16 + n];
        unsigned short hh = f2bf(x);
        h[j] = (short)hh;
        l[j] = (short)f2bf(x - bf2f(hh));
    }
    ((s16x8*)WfH)[id] = h;
    ((s16x8*)WfL)[id] = l;
}

__global__ __launch_bounds__(256) void lap_kernel(const int* __restrict__ cnt,
                                                  const int* __restrict__ csr,
                                                  const float* __restrict__ dsq,
                                                  const float* __restrict__ lm,
                                                  unsigned short* __restrict__ XrowH,
                                                  unsigned short* __restrict__ XrowL,
                                                  unsigned short* __restrict__ XfH, int p) {
    int wid  = (blockIdx.x * blockDim.x + threadIdx.x) >> 6;   // node
    int lane = threadIdx.x & 63;
    int s = lane >> 3;      // edge slot 0..7
    int o = lane & 7;       // feature octet (8 feats, 16B)
    if (wid >= NN) return;
    int n  = wid;
    int dg = min(cnt[n], CAP);
    int cin = p - 1;

    float acc[8];
    #pragma unroll
    for (int j = 0; j < 8; ++j) acc[j] = 0.f;

    for (int k = s; k < dg; k += 16) {
        int e0 = csr[n * CAP + k];
        bool pr = (k + 8) < dg;
        int e1 = pr ? csr[n * CAP + k + 8] : e0;
        float d0 = dsq[e0];
        float d1 = pr ? dsq[e1] : 0.f;
        s16x8 x0 = *(const s16x8*)&XrowH[((size_t)e0 * 3 + cin) * 64 + o * 8];
        s16x8 x1 = *(const s16x8*)&XrowH[((size_t)e1 * 3 + cin) * 64 + o * 8];
        #pragma unroll
        for (int j = 0; j < 8; ++j)
            acc[j] += bf2f(x0[j]) * d0 + bf2f(x1[j]) * d1;
    }
    #pragma unroll
    for (int j = 0; j < 8; ++j) {
        acc[j] += __shfl_xor(acc[j], 8);
        acc[j] += __shfl_xor(acc[j], 16);
        acc[j] += __shfl_xor(acc[j], 32);
    }

    float rn = 2.0f / lm[0];
    float dn = dsq[n];
    s16x8 xh = *(const s16x8*)&XrowH[((size_t)n * 3 + cin) * 64 + o * 8];
    s16x8 xl = *(const s16x8*)&XrowL[((size_t)n * 3 + cin) * 64 + o * 8];
    float r[8];
    if (p == 1) {
        float c1 = rn - 1.0f;
        #pragma unroll
        for (int j = 0; j < 8; ++j)
            r[j] = -rn * dn * acc[j] + (bf2f(xh[j]) + bf2f(xl[j])) * c1;
    } else {
        s16x8 zh = *(const s16x8*)&XrowH[((size_t)n * 3 + (p - 2)) * 64 + o * 8];
        s16x8 zl = *(const s16x8*)&XrowL[((size_t)n * 3 + (p - 2)) * 64 + o * 8];
        float c1 = 2.0f * (rn - 1.0f);
        #pragma unroll
        for (int j = 0; j < 8; ++j)
            r[j] = -2.0f * rn * dn * acc[j] + (bf2f(xh[j]) + bf2f(xl[j])) * c1
                 - (bf2f(zh[j]) + bf2f(zl[j]));
    }
    s16x8 h;
    #pragma unroll
    for (int j = 0; j < 8; ++j) h[j] = (short)f2bf(r[j]);

    if (s == 0 && p < 3) {
        *(s16x8*)&XrowH[((size_t)n * 3 + p) * 64 + o * 8] = h;
    } else if (s == 1 && p < 3) {
        s16x8 l;
        #pragma unroll
        for (int j = 0; j < 8; ++j) l[j] = (short)f2bf(r[j] - bf2f(h[j]));
        *(s16x8*)&XrowL[((size_t)n * 3 + p) * 64 + o * 8] = l;
    } else if (s == 2) {
        int t = n >> 4, m = n & 15;
        int k0 = p * 2 + (o >> 2), qq = o & 3;
        size_t chunk = (size_t)((t * 8 + k0) * 64 + qq * 16 + m);
        *(s16x8*)&XfH[chunk * 8] = h;
    }
}

__global__ __launch_bounds__(256, 2) void gemm_kernel(const unsigned short* __restrict__ XfH,
                                                      const unsigned short* __restrict__ WfH,
                                                      const unsigned short* __restrict__ WfL,
                                                      const float* __restrict__ b,
                                                      float* __restrict__ out) {
    int lane = threadIdx.x & 63;
    int w    = threadIdx.x >> 6;     // 0..3
    int rh = w & 1, cg = w >> 1;
    int m = lane & 15, q = lane >> 4;
    int rowblk = blockIdx.x >> 1;
    int ch = blockIdx.x & 1;
    int bt0 = rowblk * 8 + rh * 4;
    const s16x8* AH = (const s16x8*)XfH;
    const s16x8* BH = (const s16x8*)WfH;
    const s16x8* BL = (const s16x8*)WfL;

    f32x4 acc[4][4];
    #pragma unroll
    for (int rt = 0; rt < 4; ++rt)
        #pragma unroll
        for (int c = 0; c < 4; ++c) acc[rt][c] = (f32x4){0.f, 0.f, 0.f, 0.f};

    s16x8 a[2][4], bh[2][4], bl[2][4];
    #pragma unroll
    for (int rt = 0; rt < 4; ++rt) a[0][rt] = AH[((bt0 + rt) * 8 + 0) * 64 + lane];
    #pragma unroll
    for (int c = 0; c < 4; ++c) {
        int ct = ch * 8 + cg * 4 + c;
        bh[0][c] = BH[(ct * 8 + 0) * 64 + lane];
        bl[0][c] = BL[(ct * 8 + 0) * 64 + lane];
    }

    #pragma unroll
    for (int k0 = 0; k0 < 8; ++k0) {
        int cur = k0 & 1, nxt = cur ^ 1;
        if (k0 < 7) {
            #pragma unroll
            for (int rt = 0; rt < 4; ++rt)
                a[nxt][rt] = AH[((bt0 + rt) * 8 + k0 + 1) * 64 + lane];
            #pragma unroll
            for (int c = 0; c < 4; ++c) {
                int ct = ch * 8 + cg * 4 + c;
                bh[nxt][c] = BH[(ct * 8 + k0 + 1) * 64 + lane];
                bl[nxt][c] = BL[(ct * 8 + k0 + 1) * 64 + lane];
            }
        }
        #pragma unroll
        for (int c = 0; c < 4; ++c)
            #pragma unroll
            for (int rt = 0; rt < 4; ++rt) {
                acc[rt][c] = __builtin_amdgcn_mfma_f32_16x16x32_bf16(a[cur][rt], bh[cur][c], acc[rt][c], 0, 0, 0);
                acc[rt][c] = __builtin_amdgcn_mfma_f32_16x16x32_bf16(a[cur][rt], bl[cur][c], acc[rt][c], 0, 0, 0);
            }
    }

    #pragma unroll
    for (int rt = 0; rt < 4; ++rt) {
        int rbase = (bt0 + rt) * 16 + q * 4;
        #pragma unroll
        for (int c = 0; c < 4; ++c) {
            int col = (ch * 8 + cg * 4 + c) * 16 + m;
            float bv = b[col];
            #pragma unroll
            for (int i = 0; i < 4; ++i) {
                int r = rbase + i;
                if (r < NN) out[r * OUTF + col] = fmaxf(acc[rt][c][i] + bv, 0.0f);
            }
        }
    }
}

// ==== host ==================================================================
extern "C" void kernel_launch(void* const* d_in, const int* in_sizes, int n_in,
                              void* d_out, int out_size, void* d_ws, size_t ws_size,
                              hipStream_t stream) {
    const float* signal     = (const float*)d_in[0];
    const int*   src        = (const int*)  d_in[1];
    const int*   dst        = (const int*)  d_in[2];
    const float* lambda_max = (const float*)d_in[3];
    const float* W          = (const float*)d_in[4];
    const float* b          = (const float*)d_in[5];
    float* out = (float*)d_out;

    // ws (all int counts divisible by 4 -> 16B alignment preserved):
    // blockhist[196*196] | blockpre[196*196] | colsum[196] | bucketbase[196]
    // | cnt[NN] | dsq[NN] | csr[NN*CAP] | ebuf[NE]
    // | XrowH[NN*192]u16 | XrowL[NN*192]u16 | XfH[NT*4096]u16 | WfH/WfL[64K]u16
    // ~= 77.7 MB (R7's 80.8 MB fit)
    int*      blockhist  = (int*)d_ws;
    int*      blockpre   = blockhist + NBKT * NBLK;
    int*      colsum     = blockpre + NBKT * NBLK;
    int*      bucketbase = colsum + NBKT;                 // 196
    int*      cnt        = bucketbase + NBKT + 104;       // pad to keep /4 alignment
    float*    dsq        = (float*)(cnt + NN);
    int*      csr        = (int*)(dsq + NN);
    unsigned* ebuf       = (unsigned*)(csr + (size_t)NN * CAP);
    unsigned short* XrowH = (unsigned short*)(ebuf + NE);
    unsigned short* XrowL = XrowH + (size_t)NN * 192;
    unsigned short* XfH   = XrowL + (size_t)NN * 192;
    unsigned short* WfH   = XfH + (size_t)NT * 4096;
    unsigned short* WfL   = WfH + 65536;

    // counting-sort CSR build (no memsets, no global atomics)
    histk<<<NBLK, 1024, 0, stream>>>(dst, blockhist);
    scank<<<NBKT, 256, 0, stream>>>(blockhist, blockpre, colsum);
    bbasek<<<1, 256, 0, stream>>>(colsum, bucketbase);
    scatk<<<NBLK, 1024, 0, stream>>>(src, dst, blockpre, bucketbase, ebuf);
    buildk<<<NBKT, 256, 0, stream>>>(ebuf, bucketbase, colsum, cnt, dsq, csr);

    copy0_kernel<<<(NN * 16 + 255) / 256, 256, 0, stream>>>(signal, XrowH, XrowL, XfH);
    convw_kernel<<<32, 256, 0, stream>>>(W, WfH, WfL);

    for (int p = 1; p <= 3; ++p)
        lap_kernel<<<NN / 4, 256, 0, stream>>>(cnt, csr, dsq, lambda_max, XrowH, XrowL, XfH, p);

    gemm_kernel<<<391 * 2, 256, 0, stream>>>(XfH, WfH, WfL, b, out);
}